// Round 12
// baseline (344.320 us; speedup 1.0000x reference)
//
#include <hip/hip_runtime.h>
#include <stdint.h>

#define N_NODES 20000
#define E_EDGES 160000
#define C_DIM 32
#define OUT_DIM 128
#define K_REAL 910
#define KPH 480           // padded per-half K (448 feat + 7 e + 25 zeros), 15 x 32
#define DEG_CAP 64
#define SEG 1024
#define NSEG 20           // ceil(20000/1024)
#define MT_A (E_EDGES/256)    // 625 m-tiles, edge-row GEMM
#define NROWS_B 20224         // 79*256, node-row GEMM (rows 20000.. are zero pad)
#define MT_B (NROWS_B/256)    // 79
#define PADW ((NROWS_B - N_NODES)*KPH/2)   // msgN pad words (ints)

typedef __attribute__((ext_vector_type(4))) float f32x4;
typedef __attribute__((ext_vector_type(8))) short short8;

__device__ __forceinline__ float bf2f(unsigned short u){
  union { unsigned int i; float f; } v; v.i = ((unsigned int)u) << 16; return v.f;
}
__device__ __forceinline__ unsigned short f2bf(float f){
  union { float f; unsigned int i; } v; v.f = f;
  unsigned int i = v.i;
  unsigned int r = (i + 0x7FFFu + ((i >> 16) & 1u)) >> 16;
  return (unsigned short)r;
}
__device__ __forceinline__ float ldv(const void* p, size_t i, int isbf){
  return isbf ? bf2f(((const unsigned short*)p)[i]) : ((const float*)p)[i];
}
__device__ __forceinline__ int clampi(int v, int hi){  // [0, hi)
  return ((unsigned)v < (unsigned)hi) ? v : 0;
}

// ---------------- init: dtype sniff + ALL zero-fills (1 launch) ----------------
__global__ void k_init(const void* __restrict__ xraw, int* __restrict__ flag,
                       int* __restrict__ cnt, float* __restrict__ out_acc,
                       unsigned short* __restrict__ msgN)
{
  int tid = threadIdx.x;
  if (blockIdx.x == 0){
    __shared__ int s_bad;
    if (tid == 0) s_bad = 0;
    __syncthreads();
    float v = bf2f(((const unsigned short*)xraw)[tid * 2499]);
    if (!(fabsf(v) < 100.0f)) s_bad = 1;
    __syncthreads();
    if (tid == 0) flag[0] = s_bad ? 0 : 1; // 1 = bf16, 0 = fp32
  }
  const int Z1 = 2*N_NODES;                 // cnt ints
  const int Z2 = Z1 + N_NODES*OUT_DIM;      // + out_acc ints
  const int Z3 = Z2 + PADW;                 // + msgN pad ints
  int* padp = (int*)(msgN + (size_t)N_NODES*KPH);
  for (int i = blockIdx.x*blockDim.x + tid; i < Z3; i += gridDim.x*blockDim.x){
    if (i < Z1) cnt[i] = 0;
    else if (i < Z2) ((int*)out_acc)[i - Z1] = 0;
    else padp[i - Z2] = 0;
  }
}

// ---------------- prep: edge vectors + degree hist + W pack (block-split) ----------------
__global__ void k_prep(const void* __restrict__ pos, const void* __restrict__ W,
                       const int* __restrict__ row, const int* __restrict__ col,
                       float* __restrict__ vecn, int* __restrict__ cnt,
                       unsigned short* __restrict__ Wp,
                       const int* __restrict__ flg)
{
  int isbf = flg[0];
  if (blockIdx.x < MT_A){                      // build part
    int e = blockIdx.x*256 + threadIdx.x;
    if (e >= E_EDGES) return;
    int r = clampi(row[e], N_NODES), c = clampi(col[e], N_NODES);
    float vx = ldv(pos, (size_t)c*3+0, isbf) - ldv(pos, (size_t)r*3+0, isbf);
    float vy = ldv(pos, (size_t)c*3+1, isbf) - ldv(pos, (size_t)r*3+1, isbf);
    float vz = ldv(pos, (size_t)c*3+2, isbf) - ldv(pos, (size_t)r*3+2, isbf);
    float nn = sqrtf(vx*vx + vy*vy + vz*vz);
    f32x4 vv; vv[0]=vx; vv[1]=vy; vv[2]=vz; vv[3]=nn;
    *(f32x4*)(vecn + (size_t)e*4) = vv;
    atomicAdd(cnt + r, 1);
    atomicAdd(cnt + N_NODES + c, 1);
  } else {                                     // packw part (aligned layout)
    int i = (blockIdx.x - MT_A)*256 + threadIdx.x;
    if (i >= 2*OUT_DIM*KPH) return;
    int half = i / (OUT_DIM*KPH);
    int rem = i - half*OUT_DIM*KPH;
    int o = rem / KPH, kp = rem - o*KPH;
    float v = 0.f;
    if (kp < 448){
      int t = kp >> 6, f = kp & 63;
      v = ldv(W, (size_t)o*K_REAL + (2*t + half)*65 + f, isbf);
    } else if (kp < 455){
      int t = kp - 448;
      v = ldv(W, (size_t)o*K_REAL + (2*t + half)*65 + 64, isbf);
    }
    Wp[i] = f2bf(v);
  }
}

// ---------------- 3-phase exclusive scan over cnt[2N] ----------------
__global__ void k_scan1(const int* __restrict__ cnt, int* __restrict__ start2,
                        int* __restrict__ segsum){
  __shared__ int buf[SEG];
  int b = blockIdx.x, arr = b / NSEG, seg = b - arr*NSEG;
  const int* cntp = cnt + (size_t)arr*N_NODES;
  int* startp = start2 + (size_t)arr*(N_NODES+1);
  int tid = threadIdx.x;
  int i = seg*SEG + tid;
  int v = (i < N_NODES) ? cntp[i] : 0;
  buf[tid] = v;
  __syncthreads();
  for (int off = 1; off < SEG; off <<= 1){
    int t = (tid >= off) ? buf[tid-off] : 0;
    __syncthreads();
    buf[tid] += t;
    __syncthreads();
  }
  if (i < N_NODES) startp[i] = buf[tid] - v;
  if (tid == SEG-1) segsum[b] = buf[tid];
}
__global__ void k_scan2(int* segsum){
  int tid = threadIdx.x;
  if (tid < 2){
    int run = 0;
    for (int s = 0; s < NSEG; ++s){
      int v = segsum[tid*NSEG+s]; segsum[tid*NSEG+s] = run; run += v;
    }
  }
}
__global__ void k_scan3(int* __restrict__ start2, int* __restrict__ fill2,
                        const int* __restrict__ segsum){
  int b = blockIdx.x, arr = b / NSEG, seg = b - arr*NSEG;
  int* startp = start2 + (size_t)arr*(N_NODES+1);
  int* fillp  = fill2  + (size_t)arr*N_NODES;
  int tid = threadIdx.x;
  int i = seg*SEG + tid;
  int add = segsum[b];
  if (i < N_NODES){ int s = startp[i] + add; startp[i] = s; fillp[i] = s; }
  if (b == 0 && tid == 0){
    start2[N_NODES] = E_EDGES;
    start2[(N_NODES+1) + N_NODES] = E_EDGES;
  }
}

// ---------------- scatter edge ids into CSR lists (+ inverse col perm + node of pos) ----------------
__global__ void k_scatter(const int* __restrict__ row, const int* __restrict__ col,
                          int* fill2, int* list_row, int* list_col,
                          int* pos_col, int* node_of_pos)
{
  int e = blockIdx.x*blockDim.x + threadIdx.x;
  if (e >= E_EDGES) return;
  int r = clampi(row[e], N_NODES), c = clampi(col[e], N_NODES);
  int p = atomicAdd(fill2 + r, 1);
  if ((unsigned)p < E_EDGES) list_row[p] = e;
  int q = atomicAdd(fill2 + N_NODES + c, 1);
  if ((unsigned)q < E_EDGES){ list_col[q] = e; node_of_pos[q] = c; }
  pos_col[e] = clampi(q, E_EDGES);
}

// ---------------- merged message build: grid = 2*N, kind = blockIdx&1 ----------------
// kind 0: half-0 per-edge rows (proven k_msg_node body, half=0).
// kind 1: per-node half-1 row (proven k_msg1 block-per-node body).
// Independent work interleaved on every CU -> k_msg1's gather-latency bubbles
// fill k_msg_node's VALU gaps (heterogeneous-wave co-schedule). LDS unioned
// (17408 B = max of the two) -> 8 blocks/CU preserved.
__global__ __launch_bounds__(256)
void k_msg(const void* __restrict__ x, const void* __restrict__ eattr,
           const float* __restrict__ vecn,
           const int* __restrict__ row, const int* __restrict__ col,
           const int* __restrict__ start2,
           const int* __restrict__ list_row, const int* __restrict__ list_col,
           const int* __restrict__ pos_col,
           unsigned short* __restrict__ msg,
           unsigned short* __restrict__ msgN,
           const int* __restrict__ flg)
{
  __shared__ union {
    struct {                                   // kind 0 (17408 B)
      int posT[DEG_CAP];
      int othS[DEG_CAP];
      float vS[DEG_CAP][4], vT[DEG_CAP][4];
      float eS[DEG_CAP];
      unsigned short fS[DEG_CAP][64];
      float e64[DEG_CAP][8];
      unsigned char bins[DEG_CAP][DEG_CAP];
    } a;
    struct {                                   // kind 1 (~14.9 KB)
      float vS[DEG_CAP][4], vT[DEG_CAP][4];
      float eT[DEG_CAP];
      int othT[DEG_CAP];
      unsigned short fT[DEG_CAP][64];
      unsigned int chist[DEG_CAP][8];
      float m1acc[7][64];
      float m1e[7];
    } b;
  } sh;

  const float cb1 = 0.9009688679f, cb2 = 0.6234898019f, cb3 = 0.2225209340f;
  const int* start_row = start2;
  const int* start_col = start2 + (N_NODES+1);
  int kind = blockIdx.x & 1;
  int j = blockIdx.x >> 1;
  int tid = threadIdx.x, wv = tid >> 6, lane = tid & 63;
  int clo = start_col[j], chi = start_col[j+1];
  int rlo = start_row[j], rhi = start_row[j+1];
  if (clo < 0) clo = 0; if (chi > E_EDGES) chi = E_EDGES; if (chi < clo) chi = clo;
  if (rlo < 0) rlo = 0; if (rhi > E_EDGES) rhi = E_EDGES; if (rhi < rlo) rhi = rlo;
  int isbf = flg[0];

  if (kind == 0){
    // ---------- half-0 per-edge rows (sources = in-edges, targets = out-edges) ----------
    int nS = chi - clo, nT = rhi - rlo;
    int slo = clo, tlo = rlo;
    const int* slist = list_col;
    const int* tlist = list_row;
    if (nT == 0) return;

    if (nS <= DEG_CAP && nT <= DEG_CAP){
      int nS4 = (nS + 3) & ~3;
      if (tid < nS){
        int s = clampi(slist[slo+tid], E_EDGES);
        sh.a.othS[tid] = clampi(row[s], N_NODES);
        sh.a.eS[tid] = ldv(eattr, s, isbf);
        sh.a.vS[tid][0]=vecn[s*4+0]; sh.a.vS[tid][1]=vecn[s*4+1];
        sh.a.vS[tid][2]=vecn[s*4+2]; sh.a.vS[tid][3]=vecn[s*4+3];
      }
      if (tid < nT){
        int t = clampi(tlist[tlo+tid], E_EDGES);
        sh.a.posT[tid] = clampi(pos_col[t], E_EDGES);
        sh.a.vT[tid][0]=vecn[t*4+0]; sh.a.vT[tid][1]=vecn[t*4+1];
        sh.a.vT[tid][2]=vecn[t*4+2]; sh.a.vT[tid][3]=vecn[t*4+3];
      }
      for (int i = tid; i < DEG_CAP*8; i += 256) ((float*)sh.a.e64)[i] = 0.f;
      { uint4 z = {0,0,0,0};                       // zero bins (pad cols read as t=0)
        ((uint4*)sh.a.bins)[tid] = z; }
      __syncthreads();
      // stage source features [x[other] | x[j]]
      for (int cidx = tid; cidx < nS*64; cidx += 256){
        int si = cidx >> 6, f = cidx & 63;
        int src = (f < 32) ? (sh.a.othS[si]*C_DIM + f) : (j*C_DIM + f - 32);
        sh.a.fS[si][f] = f2bf(ldv(x, (size_t)src, isbf));
      }
      for (int i = tid; i < (nS4 - nS)*64; i += 256)
        sh.a.fS[nS + (i >> 6)][i & 63] = 0;
      // pair bins (+ eattr accumulation per (target, bin))
      for (int p = tid; p < nS*64; p += 256){
        int si = p >> 6, ti = p & 63;
        if (ti < nT){
          float dot = -(sh.a.vS[si][0]*sh.a.vT[ti][0] + sh.a.vS[si][1]*sh.a.vT[ti][1]
                      + sh.a.vS[si][2]*sh.a.vT[ti][2]);
          float cv = dot / (sh.a.vS[si][3]*sh.a.vT[ti][3] + 1e-8f);
          int t = (cv<=cb1)+(cv<=cb2)+(cv<=cb3)+(cv<=-cb3)+(cv<=-cb2)+(cv<=-cb1);
          sh.a.bins[ti][si] = (unsigned char)t;
          atomicAdd(&sh.a.e64[ti][t], sh.a.eS[si]);
        }
      }
      __syncthreads();
      for (int ti = wv; ti < nT; ti += 4){
        float S0=0,S1=0,S2=0,S3=0,S4=0,S5=0,S6=0;
        const unsigned* brow = (const unsigned*)sh.a.bins[ti];
        for (int s4 = 0; s4 < nS4; s4 += 4){
          unsigned bb = (unsigned)__builtin_amdgcn_readfirstlane((int)brow[s4 >> 2]);
          #pragma unroll
          for (int u = 0; u < 4; ++u){
            int t = (bb >> (8*u)) & 7;
            float val = bf2f(sh.a.fS[s4 + u][lane]);    // pad rows are 0
            switch(t){
              case 0: S0+=val; break; case 1: S1+=val; break; case 2: S2+=val; break;
              case 3: S3+=val; break; case 4: S4+=val; break; case 5: S5+=val; break;
              default: S6+=val; break;
            }
          }
        }
        unsigned short* mrow = msg + (size_t)sh.a.posT[ti]*KPH;
        mrow[0*64+lane]=f2bf(S0); mrow[1*64+lane]=f2bf(S1); mrow[2*64+lane]=f2bf(S2);
        mrow[3*64+lane]=f2bf(S3); mrow[4*64+lane]=f2bf(S4); mrow[5*64+lane]=f2bf(S5);
        mrow[6*64+lane]=f2bf(S6);
        if (lane < 7)  mrow[448+lane] = f2bf(sh.a.e64[ti][lane]);
        if (lane < 25) mrow[455+lane] = 0;
      }
    } else {
      // degree > cap fallback: all-global (correct, ~never taken)
      for (int ti = wv; ti < rhi - rlo; ti += 4){
        int te = clampi(tlist[tlo+ti], E_EDGES);
        float tx=vecn[te*4+0], ty=vecn[te*4+1], tz=vecn[te*4+2], tn=vecn[te*4+3];
        float S0=0,S1=0,S2=0,S3=0,S4=0,S5=0,S6=0,S64v=0;
        for (int si = 0; si < nS; ++si){
          int se = clampi(slist[slo+si], E_EDGES);
          float dot = -(vecn[se*4+0]*tx + vecn[se*4+1]*ty + vecn[se*4+2]*tz);
          float cv = dot / (vecn[se*4+3]*tn + 1e-8f);
          int tv = (cv<=cb1)+(cv<=cb2)+(cv<=cb3)+(cv<=-cb3)+(cv<=-cb2)+(cv<=-cb1);
          int t = __builtin_amdgcn_readfirstlane(tv);
          int oth = clampi(row[se], N_NODES);
          float val = (lane < 32) ? ldv(x, (size_t)oth*C_DIM+lane, isbf)
                                  : ldv(x, (size_t)j*C_DIM+lane-32, isbf);
          switch(t){
            case 0: S0+=val; break; case 1: S1+=val; break; case 2: S2+=val; break;
            case 3: S3+=val; break; case 4: S4+=val; break; case 5: S5+=val; break;
            default: S6+=val; break;
          }
          S64v += (lane == t) ? ldv(eattr, se, isbf) : 0.f;
        }
        unsigned short* mrow = msg + (size_t)clampi(pos_col[te], E_EDGES)*KPH;
        mrow[0*64+lane]=f2bf(S0); mrow[1*64+lane]=f2bf(S1); mrow[2*64+lane]=f2bf(S2);
        mrow[3*64+lane]=f2bf(S3); mrow[4*64+lane]=f2bf(S4); mrow[5*64+lane]=f2bf(S5);
        mrow[6*64+lane]=f2bf(S6);
        if (lane < 7)  mrow[448+lane] = f2bf(S64v);
        if (lane < 25) mrow[455+lane] = 0;
      }
    }
  } else {
    // ---------- per-node half-1 row (proven k_msg1 block-per-node body) ----------
    int nS = chi - clo, nT = rhi - rlo;
    unsigned short* mrow = msgN + (size_t)j*KPH;

    if (nT == 0 || nS == 0){
      for (int i = tid; i < KPH; i += 256) mrow[i] = 0;
      return;
    }
    int fast = (nS <= DEG_CAP && nT <= DEG_CAP);

    if (fast){
      if (tid < nS){
        int s = clampi(list_col[clo+tid], E_EDGES);
        sh.b.vS[tid][0]=vecn[s*4+0]; sh.b.vS[tid][1]=vecn[s*4+1];
        sh.b.vS[tid][2]=vecn[s*4+2]; sh.b.vS[tid][3]=vecn[s*4+3];
      }
      if (tid < nT){
        int t = clampi(list_row[rlo+tid], E_EDGES);
        sh.b.othT[tid] = clampi(col[t], N_NODES);
        sh.b.eT[tid] = ldv(eattr, t, isbf);
        sh.b.vT[tid][0]=vecn[t*4+0]; sh.b.vT[tid][1]=vecn[t*4+1];
        sh.b.vT[tid][2]=vecn[t*4+2]; sh.b.vT[tid][3]=vecn[t*4+3];
      }
      for (int i = tid; i < DEG_CAP*8; i += 256) ((unsigned*)sh.b.chist)[i] = 0u;
      __syncthreads();
      // stage fT = [x_j | x_oth]
      for (int cidx = tid; cidx < nT*64; cidx += 256){
        int ti = cidx >> 6, f = cidx & 63;
        int src = (f < 32) ? (j*C_DIM + f) : (sh.b.othT[ti]*C_DIM + f - 32);
        sh.b.fT[ti][f] = f2bf(ldv(x, (size_t)src, isbf));
      }
      // pair binning -> counts only (pow2-compacted over targets)
      {
        int lognT = (nT > 1) ? (32 - __builtin_clz((unsigned)(nT-1))) : 0;
        int mskT = (1 << lognT) - 1;
        for (int p = tid; p < (nS << lognT); p += 256){
          int si = p >> lognT, ti = p & mskT;
          if (ti < nT){
            float dot = -(sh.b.vS[si][0]*sh.b.vT[ti][0] + sh.b.vS[si][1]*sh.b.vT[ti][1]
                        + sh.b.vS[si][2]*sh.b.vT[ti][2]);
            float cv = dot / (sh.b.vS[si][3]*sh.b.vT[ti][3] + 1e-8f);
            int t = (cv<=cb1)+(cv<=cb2)+(cv<=cb3)+(cv<=-cb3)+(cv<=-cb2)+(cv<=-cb1);
            atomicAdd(&sh.b.chist[ti][t], 1u);
          }
        }
      }
      __syncthreads();
      // broadcast-FMA phase: wave wv handles bins t = wv, wv+4
      for (int t = wv; t < 7; t += 4){
        float m = 0.f, me = 0.f;
        for (int ti = 0; ti < nT; ++ti){
          float c = (float)sh.b.chist[ti][t];      // wave-uniform broadcast
          m  += c * bf2f(sh.b.fT[ti][lane]);
          me += c * sh.b.eT[ti];
        }
        mrow[t*64+lane] = f2bf(m);
        if (lane == 0) mrow[448+t] = f2bf(me);
      }
    } else {
      // degree > cap fallback: all-global, LDS atomics (correct, ~never taken)
      for (int i = tid; i < 448; i += 256) ((float*)sh.b.m1acc)[i] = 0.f;
      if (tid < 7) sh.b.m1e[tid] = 0.f;
      __syncthreads();
      for (int ti = wv; ti < nT; ti += 4){
        int te = clampi(list_row[rlo+ti], E_EDGES);
        float tx=vecn[te*4+0], ty=vecn[te*4+1], tz=vecn[te*4+2], tn=vecn[te*4+3];
        int oT = clampi(col[te], N_NODES);
        float eTv = ldv(eattr, te, isbf);
        float valT = (lane < 32) ? ldv(x, (size_t)j*C_DIM+lane, isbf)
                                 : ldv(x, (size_t)oT*C_DIM+lane-32, isbf);
        float c0=0,c1=0,c2=0,c3=0,c4=0,c5=0,c6=0;
        for (int si = 0; si < nS; ++si){
          int se = clampi(list_col[clo+si], E_EDGES);
          float dot = -(vecn[se*4+0]*tx + vecn[se*4+1]*ty + vecn[se*4+2]*tz);
          float cv = dot / (vecn[se*4+3]*tn + 1e-8f);
          int tv = (cv<=cb1)+(cv<=cb2)+(cv<=cb3)+(cv<=-cb3)+(cv<=-cb2)+(cv<=-cb1);
          int t = __builtin_amdgcn_readfirstlane(tv);
          switch(t){
            case 0: c0+=1.f; break; case 1: c1+=1.f; break; case 2: c2+=1.f; break;
            case 3: c3+=1.f; break; case 4: c4+=1.f; break; case 5: c5+=1.f; break;
            default: c6+=1.f; break;
          }
        }
        atomicAdd(&sh.b.m1acc[0][lane], c0*valT); atomicAdd(&sh.b.m1acc[1][lane], c1*valT);
        atomicAdd(&sh.b.m1acc[2][lane], c2*valT); atomicAdd(&sh.b.m1acc[3][lane], c3*valT);
        atomicAdd(&sh.b.m1acc[4][lane], c4*valT); atomicAdd(&sh.b.m1acc[5][lane], c5*valT);
        atomicAdd(&sh.b.m1acc[6][lane], c6*valT);
        if (lane == 0){
          atomicAdd(&sh.b.m1e[0], c0*eTv); atomicAdd(&sh.b.m1e[1], c1*eTv);
          atomicAdd(&sh.b.m1e[2], c2*eTv); atomicAdd(&sh.b.m1e[3], c3*eTv);
          atomicAdd(&sh.b.m1e[4], c4*eTv); atomicAdd(&sh.b.m1e[5], c5*eTv);
          atomicAdd(&sh.b.m1e[6], c6*eTv);
        }
      }
      __syncthreads();
      for (int t = wv; t < 7; t += 4){
        mrow[t*64+lane] = f2bf(sh.b.m1acc[t][lane]);
        if (lane == 0) mrow[448+t] = f2bf(sh.b.m1e[t]);
      }
    }
    if (tid < 25) mrow[455+tid] = 0;
  }
}

// ---------------- GEMM: B in LDS once, 3-deep A prefetch, single-phase epilogue ----------------
// Flattened grid remapped so the two ch-halves of one m-tile land 8 apart
// (same XCD under round-robin) -> second A-tile read hits that XCD's L2.
__global__ __launch_bounds__(256)
void k_gemm(const unsigned short* __restrict__ A,
            const unsigned short* __restrict__ Wp,
            const void* __restrict__ bias,
            const int* __restrict__ flg,
            const int* __restrict__ node_of_pos,
            float* __restrict__ out_acc, int addbias, int ident, int mtiles)
{
  __shared__ union {
    unsigned short Bs[64*512];     // 65536 B (60 of 64 chunk slots used per row)
    float seg[256][66];            // 67584 B, reused after K-loop
  } sh;
  __shared__ int nids[256];

  int tid = threadIdx.x;
  int w = tid >> 6, lane = tid & 63;
  int lrow = lane & 15, q = lane >> 4;

  int lin = blockIdx.x;
  const int FULLG = (mtiles & ~7) * 2;
  int mt, ch;
  if (lin < FULLG){
    mt = (lin >> 4)*8 + (lin & 7);       // ids L and L+8 share mt's A-tile
    ch = (lin >> 3) & 1;
  } else {
    int r2 = lin - FULLG;
    mt = (mtiles & ~7) + (r2 >> 1);
    ch = r2 & 1;
  }
  int m0 = mt * 256;

  nids[tid] = ident ? ((m0 + tid < N_NODES) ? m0 + tid : N_NODES-1)
                    : clampi(node_of_pos[m0 + tid], N_NODES);

  // A prologue: issue 3 k-steps of loads early (overlaps with B staging)
  const unsigned short* abase = A + (size_t)(m0 + w*64 + lrow)*KPH + q*8;
  short8 apf[3][4];
  #pragma unroll
  for (int d = 0; d < 3; ++d)
    #pragma unroll
    for (int rf = 0; rf < 4; ++rf)
      apf[d][rf] = *(const short8*)(abase + (size_t)rf*16*KPH + d*32);

  // stage B once: 64 rows x 60 chunks of 16B
  #pragma unroll
  for (int i = 0; i < 15; ++i){
    int idx = tid + i*256;
    int rr = idx / 60, cc = idx - rr*60;
    const uint4* gq = (const uint4*)(Wp + (size_t)(ch*64 + rr)*KPH + cc*8);
    *(uint4*)(sh.Bs + rr*512 + ((cc ^ (rr & 7))*8)) = *gq;
  }
  __syncthreads();

  f32x4 acc[4][4];
  #pragma unroll
  for (int rf = 0; rf < 4; ++rf)
    #pragma unroll
    for (int nf = 0; nf < 4; ++nf) acc[rf][nf] = (f32x4)0.f;

  #pragma unroll
  for (int k0i = 0; k0i < 15; ++k0i){
    int cur = k0i % 3;
    int c = k0i*4 + q;               // B chunk index 0..59
    #pragma unroll
    for (int nf = 0; nf < 4; ++nf){
      int rb = nf*16 + lrow;
      short8 bfr = *(const short8*)(sh.Bs + rb*512 + ((c ^ (rb & 7))*8));
      #pragma unroll
      for (int rf = 0; rf < 4; ++rf)
        acc[rf][nf] = __builtin_amdgcn_mfma_f32_16x16x32_bf16(apf[cur][rf], bfr, acc[rf][nf], 0, 0, 0);
    }
    if (k0i + 3 < 15){               // refill just-consumed buffer (3-step window)
      #pragma unroll
      for (int rf = 0; rf < 4; ++rf)
        apf[cur][rf] = *(const short8*)(abase + (size_t)rf*16*KPH + (k0i+3)*32);
    }
  }

  int isbf = flg[0];
  float bvs[4];
  #pragma unroll
  for (int nf = 0; nf < 4; ++nf)
    bvs[nf] = addbias ? ldv(bias, ch*64 + nf*16 + lrow, isbf) : 0.f;

  // single-phase epilogue: all waves dump fragments, then 4 groups reduce concurrently
  __syncthreads();                   // Bs dead from here
  #pragma unroll
  for (int rf = 0; rf < 4; ++rf)
    #pragma unroll
    for (int r = 0; r < 4; ++r){
      int m = w*64 + rf*16 + q*4 + r;
      #pragma unroll
      for (int nf = 0; nf < 4; ++nf)
        sh.seg[m][nf*16 + lrow] = acc[rf][nf][r] + bvs[nf];
    }
  __syncthreads();
  {
    int o = tid & 63, g = tid >> 6;  // 4 groups x 64 rows
    int base = g*64;
    float s = 0.f;
    int curn = nids[base];
    for (int r = 0; r < 64; ++r){
      int m = base + r;
      int nid = nids[m];
      if (nid != curn){
        atomicAdd(out_acc + (size_t)curn*OUT_DIM + ch*64 + o, s);
        s = 0.f; curn = nid;
      }
      s += sh.seg[m][o];
    }
    atomicAdd(out_acc + (size_t)curn*OUT_DIM + ch*64 + o, s);
  }
}

// ---------------- convert out_acc -> d_out per flag ----------------
__global__ void k_out(const float* __restrict__ acc, void* __restrict__ outp,
                      const int* __restrict__ flg){
  int i = blockIdx.x*blockDim.x + threadIdx.x;
  if (i >= N_NODES*OUT_DIM) return;
  if (flg[0]) ((unsigned short*)outp)[i] = f2bf(acc[i]);
  else        ((float*)outp)[i] = acc[i];
}

extern "C" void kernel_launch(void* const* d_in, const int* in_sizes, int n_in,
                              void* d_out, int out_size, void* d_ws, size_t ws_size,
                              hipStream_t stream)
{
  const void* x     = d_in[0];
  const void* eattr = d_in[1];
  const void* pos   = d_in[2];
  const void* W     = d_in[3];
  const void* bmsg  = d_in[4];
  const int* eidx = (const int*)d_in[5];
  const int* row = eidx;
  const int* col = eidx + E_EDGES;

  char* ws = (char*)d_ws;
  size_t off = 0;
  auto alloc = [&](size_t b){ size_t o = off; off += (b + 255) & ~(size_t)255; return o; };

  int* dflag        = (int*)(ws + alloc(256));
  float* vecn       = (float*)(ws + alloc((size_t)E_EDGES*16));
  int* cnt          = (int*)(ws + alloc((size_t)2*N_NODES*4));
  int* start2       = (int*)(ws + alloc((size_t)2*(N_NODES+1)*4));
  int* fill2        = (int*)(ws + alloc((size_t)2*N_NODES*4));
  int* segsum       = (int*)(ws + alloc((size_t)2*NSEG*4));
  int* list_row     = (int*)(ws + alloc((size_t)E_EDGES*4));
  int* list_col     = (int*)(ws + alloc((size_t)E_EDGES*4));
  int* pos_col      = (int*)(ws + alloc((size_t)E_EDGES*4));
  int* node_of_pos  = (int*)(ws + alloc((size_t)E_EDGES*4));
  unsigned short* Wp = (unsigned short*)(ws + alloc((size_t)2*OUT_DIM*KPH*2));
  float* out_acc    = (float*)(ws + alloc((size_t)N_NODES*OUT_DIM*4));
  unsigned short* msgN = (unsigned short*)(ws + alloc((size_t)NROWS_B*KPH*2));
  unsigned short* msg  = (unsigned short*)(ws + alloc((size_t)E_EDGES*KPH*2));
  (void)off; // ~190 MB total, fits the 256 MiB workspace

  unsigned short* Wp_in  = Wp;
  unsigned short* Wp_out = Wp + (size_t)OUT_DIM*KPH;

  // 1) sniff + all zero-fills
  k_init<<<2048, 256, 0, stream>>>(x, dflag, cnt, out_acc, msgN);
  // 2) edge vectors + degree hist + W pack
  k_prep<<<MT_A + 480, 256, 0, stream>>>(pos, W, row, col, vecn, cnt, Wp, dflag);
  // 3-5) scan (unchanged, proven)
  k_scan1<<<2*NSEG, SEG, 0, stream>>>(cnt, start2, segsum);
  k_scan2<<<1, 64, 0, stream>>>(segsum);
  k_scan3<<<2*NSEG, SEG, 0, stream>>>(start2, fill2, segsum);
  // 6) CSR scatter
  k_scatter<<<(E_EDGES+255)/256, 256, 0, stream>>>(row, col, fill2,
                                                   list_row, list_col, pos_col, node_of_pos);
  // 7) merged message build: both halves' blocks interleaved on every CU
  k_msg<<<2*N_NODES, 256, 0, stream>>>(x, eattr, vecn, row, col, start2,
                                       list_row, list_col, pos_col, msg, msgN, dflag);
  // 8) GEMM-A: edge rows (bias added per edge row, segment-summed by dest node)
  k_gemm<<<dim3(2*MT_A), 256, 0, stream>>>(msg, Wp_in, bmsg, dflag,
                                           node_of_pos, out_acc, 1, 0, MT_A);
  // 9) GEMM-B: node rows (half-1 collapsed; no bias; row id == node id)
  k_gemm<<<dim3(2*MT_B), 256, 0, stream>>>(msgN, Wp_out, bmsg, dflag,
                                           node_of_pos, out_acc, 0, 1, MT_B);
  // 10) emit
  k_out<<<(N_NODES*OUT_DIM+255)/256, 256, 0, stream>>>(out_acc, d_out, dflag);
}

// Round 13
// 310.084 us; speedup vs baseline: 1.1104x; 1.1104x over previous
//
#include <hip/hip_runtime.h>
#include <stdint.h>

#define N_NODES 20000
#define E_EDGES 160000
#define C_DIM 32
#define OUT_DIM 128
#define K_REAL 910
#define KPH 480           // padded per-half K (448 feat + 7 e + 25 zeros), 15 x 32
#define DEG_CAP 64
#define SEG 1024
#define NSEG 20           // ceil(20000/1024)
#define MT_A (E_EDGES/256)    // 625 m-tiles, edge-row GEMM
#define NROWS_B 20224         // 79*256, node-row GEMM (rows 20000.. are zero pad)
#define MT_B (NROWS_B/256)    // 79
#define PADW ((NROWS_B - N_NODES)*KPH/2)   // msgN pad words (ints)

typedef __attribute__((ext_vector_type(4))) float f32x4;
typedef __attribute__((ext_vector_type(8))) short short8;

__device__ __forceinline__ float bf2f(unsigned short u){
  union { unsigned int i; float f; } v; v.i = ((unsigned int)u) << 16; return v.f;
}
__device__ __forceinline__ unsigned short f2bf(float f){
  union { float f; unsigned int i; } v; v.f = f;
  unsigned int i = v.i;
  unsigned int r = (i + 0x7FFFu + ((i >> 16) & 1u)) >> 16;
  return (unsigned short)r;
}
__device__ __forceinline__ float ldv(const void* p, size_t i, int isbf){
  return isbf ? bf2f(((const unsigned short*)p)[i]) : ((const float*)p)[i];
}
__device__ __forceinline__ int clampi(int v, int hi){  // [0, hi)
  return ((unsigned)v < (unsigned)hi) ? v : 0;
}

// ---------------- init: dtype sniff + ALL zero-fills (1 launch) ----------------
__global__ void k_init(const void* __restrict__ xraw, int* __restrict__ flag,
                       int* __restrict__ cnt, float* __restrict__ out_acc,
                       unsigned short* __restrict__ msgN)
{
  int tid = threadIdx.x;
  if (blockIdx.x == 0){
    __shared__ int s_bad;
    if (tid == 0) s_bad = 0;
    __syncthreads();
    float v = bf2f(((const unsigned short*)xraw)[tid * 2499]);
    if (!(fabsf(v) < 100.0f)) s_bad = 1;
    __syncthreads();
    if (tid == 0) flag[0] = s_bad ? 0 : 1; // 1 = bf16, 0 = fp32
  }
  const int Z1 = 2*N_NODES;                 // cnt ints
  const int Z2 = Z1 + N_NODES*OUT_DIM;      // + out_acc ints
  const int Z3 = Z2 + PADW;                 // + msgN pad ints
  int* padp = (int*)(msgN + (size_t)N_NODES*KPH);
  for (int i = blockIdx.x*blockDim.x + tid; i < Z3; i += gridDim.x*blockDim.x){
    if (i < Z1) cnt[i] = 0;
    else if (i < Z2) ((int*)out_acc)[i - Z1] = 0;
    else padp[i - Z2] = 0;
  }
}

// ---------------- prep: edge vectors + degree hist + W pack (block-split) ----------------
__global__ void k_prep(const void* __restrict__ pos, const void* __restrict__ W,
                       const int* __restrict__ row, const int* __restrict__ col,
                       float* __restrict__ vecn, int* __restrict__ cnt,
                       unsigned short* __restrict__ Wp,
                       const int* __restrict__ flg)
{
  int isbf = flg[0];
  if (blockIdx.x < MT_A){                      // build part
    int e = blockIdx.x*256 + threadIdx.x;
    if (e >= E_EDGES) return;
    int r = clampi(row[e], N_NODES), c = clampi(col[e], N_NODES);
    float vx = ldv(pos, (size_t)c*3+0, isbf) - ldv(pos, (size_t)r*3+0, isbf);
    float vy = ldv(pos, (size_t)c*3+1, isbf) - ldv(pos, (size_t)r*3+1, isbf);
    float vz = ldv(pos, (size_t)c*3+2, isbf) - ldv(pos, (size_t)r*3+2, isbf);
    float nn = sqrtf(vx*vx + vy*vy + vz*vz);
    f32x4 vv; vv[0]=vx; vv[1]=vy; vv[2]=vz; vv[3]=nn;
    *(f32x4*)(vecn + (size_t)e*4) = vv;
    atomicAdd(cnt + r, 1);
    atomicAdd(cnt + N_NODES + c, 1);
  } else {                                     // packw part (aligned layout)
    int i = (blockIdx.x - MT_A)*256 + threadIdx.x;
    if (i >= 2*OUT_DIM*KPH) return;
    int half = i / (OUT_DIM*KPH);
    int rem = i - half*OUT_DIM*KPH;
    int o = rem / KPH, kp = rem - o*KPH;
    float v = 0.f;
    if (kp < 448){
      int t = kp >> 6, f = kp & 63;
      v = ldv(W, (size_t)o*K_REAL + (2*t + half)*65 + f, isbf);
    } else if (kp < 455){
      int t = kp - 448;
      v = ldv(W, (size_t)o*K_REAL + (2*t + half)*65 + 64, isbf);
    }
    Wp[i] = f2bf(v);
  }
}

// ---------------- 3-phase exclusive scan over cnt[2N] ----------------
__global__ void k_scan1(const int* __restrict__ cnt, int* __restrict__ start2,
                        int* __restrict__ segsum){
  __shared__ int buf[SEG];
  int b = blockIdx.x, arr = b / NSEG, seg = b - arr*NSEG;
  const int* cntp = cnt + (size_t)arr*N_NODES;
  int* startp = start2 + (size_t)arr*(N_NODES+1);
  int tid = threadIdx.x;
  int i = seg*SEG + tid;
  int v = (i < N_NODES) ? cntp[i] : 0;
  buf[tid] = v;
  __syncthreads();
  for (int off = 1; off < SEG; off <<= 1){
    int t = (tid >= off) ? buf[tid-off] : 0;
    __syncthreads();
    buf[tid] += t;
    __syncthreads();
  }
  if (i < N_NODES) startp[i] = buf[tid] - v;
  if (tid == SEG-1) segsum[b] = buf[tid];
}
__global__ void k_scan2(int* segsum){
  int tid = threadIdx.x;
  if (tid < 2){
    int run = 0;
    for (int s = 0; s < NSEG; ++s){
      int v = segsum[tid*NSEG+s]; segsum[tid*NSEG+s] = run; run += v;
    }
  }
}
__global__ void k_scan3(int* __restrict__ start2, int* __restrict__ fill2,
                        const int* __restrict__ segsum){
  int b = blockIdx.x, arr = b / NSEG, seg = b - arr*NSEG;
  int* startp = start2 + (size_t)arr*(N_NODES+1);
  int* fillp  = fill2  + (size_t)arr*N_NODES;
  int tid = threadIdx.x;
  int i = seg*SEG + tid;
  int add = segsum[b];
  if (i < N_NODES){ int s = startp[i] + add; startp[i] = s; fillp[i] = s; }
  if (b == 0 && tid == 0){
    start2[N_NODES] = E_EDGES;
    start2[(N_NODES+1) + N_NODES] = E_EDGES;
  }
}

// ---------------- scatter edge ids into CSR lists (+ inverse col perm + node of pos) ----------------
__global__ void k_scatter(const int* __restrict__ row, const int* __restrict__ col,
                          int* fill2, int* list_row, int* list_col,
                          int* pos_col, int* node_of_pos)
{
  int e = blockIdx.x*blockDim.x + threadIdx.x;
  if (e >= E_EDGES) return;
  int r = clampi(row[e], N_NODES), c = clampi(col[e], N_NODES);
  int p = atomicAdd(fill2 + r, 1);
  if ((unsigned)p < E_EDGES) list_row[p] = e;
  int q = atomicAdd(fill2 + N_NODES + c, 1);
  if ((unsigned)q < E_EDGES){ list_col[q] = e; node_of_pos[q] = c; }
  pos_col[e] = clampi(q, E_EDGES);
}

// ---------------- node-centric message build (R11-proven + cntb export in epilogue) ----------------
// Inner loop, binning, and msg-row stores byte-identical to R11. Added ONLY in
// the per-target epilogue: ballot-count the bins row (already in LDS) and store
// one 8B count word per edge -> k_msg1 no longer needs any binning or chist.
__global__ __launch_bounds__(256)
void k_msg_node(const void* __restrict__ x, const void* __restrict__ eattr,
                const float* __restrict__ vecn,
                const int* __restrict__ row, const int* __restrict__ col,
                const int* __restrict__ start2,
                const int* __restrict__ list_row, const int* __restrict__ list_col,
                const int* __restrict__ pos_col,
                unsigned short* __restrict__ msg,
                uint2* __restrict__ cntb,
                const int* __restrict__ flg, int half)
{
  __shared__ int posT[DEG_CAP];
  __shared__ int othS[DEG_CAP];
  __shared__ float vS[DEG_CAP][4], vT[DEG_CAP][4];
  __shared__ float eS[DEG_CAP];
  __shared__ unsigned short fS[DEG_CAP][64];       // bf16: keeps LDS at 17.4 KB -> 8 blocks/CU
  __shared__ float e64[DEG_CAP][8];
  __shared__ unsigned char bins[DEG_CAP][DEG_CAP]; // [target][source], 0-padded

  const float cb1 = 0.9009688679f, cb2 = 0.6234898019f, cb3 = 0.2225209340f;
  const int* start_row = start2;
  const int* start_col = start2 + (N_NODES+1);
  int j = blockIdx.x;
  int tid = threadIdx.x, wv = tid >> 6, lane = tid & 63;
  int clo = start_col[j], chi = start_col[j+1];
  int rlo = start_row[j], rhi = start_row[j+1];
  if (clo < 0) clo = 0; if (chi > E_EDGES) chi = E_EDGES; if (chi < clo) chi = clo;
  if (rlo < 0) rlo = 0; if (rhi > E_EDGES) rhi = E_EDGES; if (rhi < rlo) rhi = rlo;
  int nI = chi - clo, nO = rhi - rlo;
  int nS = half ? nO : nI;
  int nT = half ? nI : nO;
  int slo = half ? rlo : clo;
  int tlo = half ? clo : rlo;
  const int* slist = half ? list_row : list_col;
  const int* tlist = half ? list_col : list_row;
  if (nT == 0) return;
  int isbf = flg[0];

  if (nS <= DEG_CAP && nT <= DEG_CAP){
    int nS4 = (nS + 3) & ~3;
    if (tid < nS){
      int s = clampi(slist[slo+tid], E_EDGES);
      othS[tid] = clampi(half ? col[s] : row[s], N_NODES);
      eS[tid] = ldv(eattr, s, isbf);
      vS[tid][0]=vecn[s*4+0]; vS[tid][1]=vecn[s*4+1];
      vS[tid][2]=vecn[s*4+2]; vS[tid][3]=vecn[s*4+3];
    }
    if (tid < nT){
      int t = clampi(tlist[tlo+tid], E_EDGES);
      posT[tid] = clampi(pos_col[t], E_EDGES);
      vT[tid][0]=vecn[t*4+0]; vT[tid][1]=vecn[t*4+1];
      vT[tid][2]=vecn[t*4+2]; vT[tid][3]=vecn[t*4+3];
    }
    for (int i = tid; i < DEG_CAP*8; i += 256) ((float*)e64)[i] = 0.f;
    { uint4 z = {0,0,0,0};                       // zero bins (pad cols read as t=0)
      ((uint4*)bins)[tid] = z; }
    __syncthreads();
    // stage source features: half=0 -> [x[other]|x[j]], half=1 -> [x[j]|x[other]]
    for (int cidx = tid; cidx < nS*64; cidx += 256){
      int si = cidx >> 6, f = cidx & 63;
      int lo_node = half ? j : othS[si];
      int hi_node = half ? othS[si] : j;
      int src = (f < 32) ? (lo_node*C_DIM + f) : (hi_node*C_DIM + f - 32);
      fS[si][f] = f2bf(ldv(x, (size_t)src, isbf));
    }
    // zero pad rows [nS, nS4) so pad (t=0) adds 0 to S0
    for (int i = tid; i < (nS4 - nS)*64; i += 256)
      fS[nS + (i >> 6)][i & 63] = 0;
    // pair bins (+ eattr accumulation per (target, bin))
    for (int p = tid; p < nS*64; p += 256){
      int si = p >> 6, ti = p & 63;
      if (ti < nT){
        float dot = -(vS[si][0]*vT[ti][0] + vS[si][1]*vT[ti][1] + vS[si][2]*vT[ti][2]);
        float cv = dot / (vS[si][3]*vT[ti][3] + 1e-8f);
        int t = (cv<=cb1)+(cv<=cb2)+(cv<=cb3)+(cv<=-cb3)+(cv<=-cb2)+(cv<=-cb1);
        bins[ti][si] = (unsigned char)t;
        atomicAdd(&e64[ti][t], eS[si]);
      }
    }
    __syncthreads();
    for (int ti = wv; ti < nT; ti += 4){
      float S0=0,S1=0,S2=0,S3=0,S4=0,S5=0,S6=0;
      const unsigned* brow = (const unsigned*)bins[ti];
      for (int s4 = 0; s4 < nS4; s4 += 4){
        // bins row is wave-uniform -> scalarize the bin dispatch
        unsigned bb = (unsigned)__builtin_amdgcn_readfirstlane((int)brow[s4 >> 2]);
        #pragma unroll
        for (int u = 0; u < 4; ++u){
          int t = (bb >> (8*u)) & 7;
          float val = bf2f(fS[s4 + u][lane]);    // pad rows are 0
          switch(t){
            case 0: S0+=val; break; case 1: S1+=val; break; case 2: S2+=val; break;
            case 3: S3+=val; break; case 4: S4+=val; break; case 5: S5+=val; break;
            default: S6+=val; break;
          }
        }
      }
      // aligned layout: feature stores at t*64 -> 64B-aligned 128B segments
      unsigned short* mrow = msg + (size_t)posT[ti]*KPH;
      mrow[0*64+lane]=f2bf(S0); mrow[1*64+lane]=f2bf(S1); mrow[2*64+lane]=f2bf(S2);
      mrow[3*64+lane]=f2bf(S3); mrow[4*64+lane]=f2bf(S4); mrow[5*64+lane]=f2bf(S5);
      mrow[6*64+lane]=f2bf(S6);
      if (lane < 7)  mrow[448+lane] = f2bf(e64[ti][lane]);
      if (lane < 25) mrow[455+lane] = 0;
      // cntb export: ballot-count this target's bins row (epilogue-only add)
      int myb = (lane < nS) ? (int)bins[ti][lane] : 7;
      unsigned n0 = (unsigned)__popcll(__ballot(myb==0));
      unsigned n1 = (unsigned)__popcll(__ballot(myb==1));
      unsigned n2 = (unsigned)__popcll(__ballot(myb==2));
      unsigned n3 = (unsigned)__popcll(__ballot(myb==3));
      unsigned n4 = (unsigned)__popcll(__ballot(myb==4));
      unsigned n5 = (unsigned)__popcll(__ballot(myb==5));
      unsigned n6 = (unsigned)__popcll(__ballot(myb==6));
      if (lane == 0){
        uint2 cw;
        cw.x = n0 | (n1<<8) | (n2<<16) | (n3<<24);
        cw.y = n4 | (n5<<8) | (n6<<16);
        cntb[posT[ti]] = cw;
      }
    }
  } else {
    // degree > cap fallback: all-global (correct, ~never taken)
    for (int ti = wv; ti < nT; ti += 4){
      int te = clampi(tlist[tlo+ti], E_EDGES);
      float tx=vecn[te*4+0], ty=vecn[te*4+1], tz=vecn[te*4+2], tn=vecn[te*4+3];
      float S0=0,S1=0,S2=0,S3=0,S4=0,S5=0,S6=0,S64v=0;
      int n0=0,n1=0,n2=0,n3=0,n4=0,n5=0,n6=0;
      for (int si = 0; si < nS; ++si){
        int se = clampi(slist[slo+si], E_EDGES);
        float dot = -(vecn[se*4+0]*tx + vecn[se*4+1]*ty + vecn[se*4+2]*tz);
        float cv = dot / (vecn[se*4+3]*tn + 1e-8f);
        int tv = (cv<=cb1)+(cv<=cb2)+(cv<=cb3)+(cv<=-cb3)+(cv<=-cb2)+(cv<=-cb1);
        int t = __builtin_amdgcn_readfirstlane(tv);
        int oth = clampi(half ? col[se] : row[se], N_NODES);
        int lo_node = half ? j : oth;
        int hi_node = half ? oth : j;
        float val = (lane < 32) ? ldv(x, (size_t)lo_node*C_DIM+lane, isbf)
                                : ldv(x, (size_t)hi_node*C_DIM+lane-32, isbf);
        switch(t){
          case 0: S0+=val; n0++; break; case 1: S1+=val; n1++; break;
          case 2: S2+=val; n2++; break; case 3: S3+=val; n3++; break;
          case 4: S4+=val; n4++; break; case 5: S5+=val; n5++; break;
          default: S6+=val; n6++; break;
        }
        S64v += (lane == t) ? ldv(eattr, se, isbf) : 0.f;
      }
      unsigned short* mrow = msg + (size_t)clampi(pos_col[te], E_EDGES)*KPH;
      mrow[0*64+lane]=f2bf(S0); mrow[1*64+lane]=f2bf(S1); mrow[2*64+lane]=f2bf(S2);
      mrow[3*64+lane]=f2bf(S3); mrow[4*64+lane]=f2bf(S4); mrow[5*64+lane]=f2bf(S5);
      mrow[6*64+lane]=f2bf(S6);
      if (lane < 7)  mrow[448+lane] = f2bf(S64v);
      if (lane < 25) mrow[455+lane] = 0;
      if (lane == 0){
        uint2 cw;
        cw.x = (unsigned)min(n0,255) | ((unsigned)min(n1,255)<<8)
             | ((unsigned)min(n2,255)<<16) | ((unsigned)min(n3,255)<<24);
        cw.y = (unsigned)min(n4,255) | ((unsigned)min(n5,255)<<8)
             | ((unsigned)min(n6,255)<<16);
        cntb[clampi(pos_col[te], E_EDGES)] = cw;
      }
    }
  }
}

// ---------------- half-1 node rows from exported counts (R8-proven, no binning) ----------------
// MSG1[j,t,:] = sum_{out-edges b of j} cnt_t(b) * [x_j | x_col[b] | e_b].
// Counts come from k_msg_node's cntb -> no vecn staging, no pair binning, no
// chist LDS atomics (which carried ~2.6M bank conflicts). Wave-per-node with
// lane-parallel metadata + 8-deep shfl-broadcast gather window.
__global__ __launch_bounds__(256)
void k_msg1(const void* __restrict__ x, const void* __restrict__ eattr,
            const int* __restrict__ col,
            const int* __restrict__ start2,
            const int* __restrict__ list_row, const int* __restrict__ pos_col,
            const uint2* __restrict__ cntb,
            unsigned short* __restrict__ msgN,
            const int* __restrict__ flg)
{
  int wv = threadIdx.x >> 6, lane = threadIdx.x & 63;
  int j = blockIdx.x*4 + wv;
  if (j >= N_NODES) return;
  int isbf = flg[0];
  unsigned short* mrow = msgN + (size_t)j*KPH;
  int rlo = start2[j], rhi = start2[j+1];
  if (rlo < 0) rlo = 0; if (rhi > E_EDGES) rhi = E_EDGES; if (rhi < rlo) rhi = rlo;
  int nT = rhi - rlo;
  if (nT == 0){
    for (int i = lane; i < KPH; i += 64) mrow[i] = 0;
    return;
  }
  float xj = ldv(x, (size_t)j*C_DIM + (lane & 31), isbf);
  float m0=0,m1=0,m2=0,m3=0,m4=0,m5=0,m6=0;
  float me0=0,me1=0,me2=0,me3=0,me4=0,me5=0,me6=0;

  for (int tb = 0; tb < nT; tb += 64){
    int nn = nT - tb; if (nn > 64) nn = 64;
    // lane-parallel metadata for this chunk of targets
    int ok = lane < nn;
    int te = ok ? clampi(list_row[rlo + tb + lane], E_EDGES) : 0;
    int pp = clampi(pos_col[te], E_EDGES);
    uint2 cw = cntb[pp];
    int oL = clampi(col[te], N_NODES);
    float eL = ok ? ldv(eattr, te, isbf) : 0.f;
    unsigned cxL = ok ? cw.x : 0u;
    unsigned cyL = ok ? cw.y : 0u;

    for (int u = 0; u < nn; u += 8){
      float v[8], ea[8];
      unsigned cxa[8], cya[8];
      #pragma unroll
      for (int q = 0; q < 8; ++q){
        int ti = u + q;
        int o = __shfl(oL, ti);
        unsigned cx = (unsigned)__shfl((int)cxL, ti);
        unsigned cy = (unsigned)__shfl((int)cyL, ti);
        float eb = __shfl(eL, ti);
        if (ti < nn){
          v[q] = (lane < 32) ? xj : ldv(x, (size_t)o*C_DIM + lane - 32, isbf);
          cxa[q] = cx; cya[q] = cy; ea[q] = eb;
        } else {
          v[q] = 0.f; cxa[q] = 0u; cya[q] = 0u; ea[q] = 0.f;
        }
      }
      #pragma unroll
      for (int q = 0; q < 8; ++q){
        float n0=(float)(cxa[q]&255u),  n1=(float)((cxa[q]>>8)&255u),
              n2=(float)((cxa[q]>>16)&255u), n3=(float)(cxa[q]>>24),
              n4=(float)(cya[q]&255u),  n5=(float)((cya[q]>>8)&255u),
              n6=(float)((cya[q]>>16)&255u);
        m0+=n0*v[q]; m1+=n1*v[q]; m2+=n2*v[q]; m3+=n3*v[q];
        m4+=n4*v[q]; m5+=n5*v[q]; m6+=n6*v[q];
        me0+=n0*ea[q]; me1+=n1*ea[q]; me2+=n2*ea[q]; me3+=n3*ea[q];
        me4+=n4*ea[q]; me5+=n5*ea[q]; me6+=n6*ea[q];
      }
    }
  }

  mrow[0*64+lane]=f2bf(m0); mrow[1*64+lane]=f2bf(m1); mrow[2*64+lane]=f2bf(m2);
  mrow[3*64+lane]=f2bf(m3); mrow[4*64+lane]=f2bf(m4); mrow[5*64+lane]=f2bf(m5);
  mrow[6*64+lane]=f2bf(m6);
  if (lane < 7){
    float me = (lane==0)?me0:(lane==1)?me1:(lane==2)?me2:(lane==3)?me3
             : (lane==4)?me4:(lane==5)?me5:me6;
    mrow[448+lane] = f2bf(me);
  }
  if (lane < 25) mrow[455+lane] = 0;
}

// ---------------- GEMM: B in LDS once, 3-deep A prefetch, single-phase epilogue ----------------
// Flattened grid remapped so the two ch-halves of one m-tile land 8 apart
// (same XCD under round-robin) -> second A-tile read hits that XCD's L2.
__global__ __launch_bounds__(256)
void k_gemm(const unsigned short* __restrict__ A,
            const unsigned short* __restrict__ Wp,
            const void* __restrict__ bias,
            const int* __restrict__ flg,
            const int* __restrict__ node_of_pos,
            float* __restrict__ out_acc, int addbias, int ident, int mtiles)
{
  __shared__ union {
    unsigned short Bs[64*512];     // 65536 B (60 of 64 chunk slots used per row)
    float seg[256][66];            // 67584 B, reused after K-loop
  } sh;
  __shared__ int nids[256];

  int tid = threadIdx.x;
  int w = tid >> 6, lane = tid & 63;
  int lrow = lane & 15, q = lane >> 4;

  int lin = blockIdx.x;
  const int FULLG = (mtiles & ~7) * 2;
  int mt, ch;
  if (lin < FULLG){
    mt = (lin >> 4)*8 + (lin & 7);       // ids L and L+8 share mt's A-tile
    ch = (lin >> 3) & 1;
  } else {
    int r2 = lin - FULLG;
    mt = (mtiles & ~7) + (r2 >> 1);
    ch = r2 & 1;
  }
  int m0 = mt * 256;

  nids[tid] = ident ? ((m0 + tid < N_NODES) ? m0 + tid : N_NODES-1)
                    : clampi(node_of_pos[m0 + tid], N_NODES);

  // A prologue: issue 3 k-steps of loads early (overlaps with B staging)
  const unsigned short* abase = A + (size_t)(m0 + w*64 + lrow)*KPH + q*8;
  short8 apf[3][4];
  #pragma unroll
  for (int d = 0; d < 3; ++d)
    #pragma unroll
    for (int rf = 0; rf < 4; ++rf)
      apf[d][rf] = *(const short8*)(abase + (size_t)rf*16*KPH + d*32);

  // stage B once: 64 rows x 60 chunks of 16B
  #pragma unroll
  for (int i = 0; i < 15; ++i){
    int idx = tid + i*256;
    int rr = idx / 60, cc = idx - rr*60;
    const uint4* gq = (const uint4*)(Wp + (size_t)(ch*64 + rr)*KPH + cc*8);
    *(uint4*)(sh.Bs + rr*512 + ((cc ^ (rr & 7))*8)) = *gq;
  }
  __syncthreads();

  f32x4 acc[4][4];
  #pragma unroll
  for (int rf = 0; rf < 4; ++rf)
    #pragma unroll
    for (int nf = 0; nf < 4; ++nf) acc[rf][nf] = (f32x4)0.f;

  #pragma unroll
  for (int k0i = 0; k0i < 15; ++k0i){
    int cur = k0i % 3;
    int c = k0i*4 + q;               // B chunk index 0..59
    #pragma unroll
    for (int nf = 0; nf < 4; ++nf){
      int rb = nf*16 + lrow;
      short8 bfr = *(const short8*)(sh.Bs + rb*512 + ((c ^ (rb & 7))*8));
      #pragma unroll
      for (int rf = 0; rf < 4; ++rf)
        acc[rf][nf] = __builtin_amdgcn_mfma_f32_16x16x32_bf16(apf[cur][rf], bfr, acc[rf][nf], 0, 0, 0);
    }
    if (k0i + 3 < 15){               // refill just-consumed buffer (3-step window)
      #pragma unroll
      for (int rf = 0; rf < 4; ++rf)
        apf[cur][rf] = *(const short8*)(abase + (size_t)rf*16*KPH + (k0i+3)*32);
    }
  }

  int isbf = flg[0];
  float bvs[4];
  #pragma unroll
  for (int nf = 0; nf < 4; ++nf)
    bvs[nf] = addbias ? ldv(bias, ch*64 + nf*16 + lrow, isbf) : 0.f;

  // single-phase epilogue: all waves dump fragments, then 4 groups reduce concurrently
  __syncthreads();                   // Bs dead from here
  #pragma unroll
  for (int rf = 0; rf < 4; ++rf)
    #pragma unroll
    for (int r = 0; r < 4; ++r){
      int m = w*64 + rf*16 + q*4 + r;
      #pragma unroll
      for (int nf = 0; nf < 4; ++nf)
        sh.seg[m][nf*16 + lrow] = acc[rf][nf][r] + bvs[nf];
    }
  __syncthreads();
  {
    int o = tid & 63, g = tid >> 6;  // 4 groups x 64 rows
    int base = g*64;
    float s = 0.f;
    int curn = nids[base];
    for (int r = 0; r < 64; ++r){
      int m = base + r;
      int nid = nids[m];
      if (nid != curn){
        atomicAdd(out_acc + (size_t)curn*OUT_DIM + ch*64 + o, s);
        s = 0.f; curn = nid;
      }
      s += sh.seg[m][o];
    }
    atomicAdd(out_acc + (size_t)curn*OUT_DIM + ch*64 + o, s);
  }
}

// ---------------- convert out_acc -> d_out per flag ----------------
__global__ void k_out(const float* __restrict__ acc, void* __restrict__ outp,
                      const int* __restrict__ flg){
  int i = blockIdx.x*blockDim.x + threadIdx.x;
  if (i >= N_NODES*OUT_DIM) return;
  if (flg[0]) ((unsigned short*)outp)[i] = f2bf(acc[i]);
  else        ((float*)outp)[i] = acc[i];
}

extern "C" void kernel_launch(void* const* d_in, const int* in_sizes, int n_in,
                              void* d_out, int out_size, void* d_ws, size_t ws_size,
                              hipStream_t stream)
{
  const void* x     = d_in[0];
  const void* eattr = d_in[1];
  const void* pos   = d_in[2];
  const void* W     = d_in[3];
  const void* bmsg  = d_in[4];
  const int* eidx = (const int*)d_in[5];
  const int* row = eidx;
  const int* col = eidx + E_EDGES;

  char* ws = (char*)d_ws;
  size_t off = 0;
  auto alloc = [&](size_t b){ size_t o = off; off += (b + 255) & ~(size_t)255; return o; };

  int* dflag        = (int*)(ws + alloc(256));
  float* vecn       = (float*)(ws + alloc((size_t)E_EDGES*16));
  int* cnt          = (int*)(ws + alloc((size_t)2*N_NODES*4));
  int* start2       = (int*)(ws + alloc((size_t)2*(N_NODES+1)*4));
  int* fill2        = (int*)(ws + alloc((size_t)2*N_NODES*4));
  int* segsum       = (int*)(ws + alloc((size_t)2*NSEG*4));
  int* list_row     = (int*)(ws + alloc((size_t)E_EDGES*4));
  int* list_col     = (int*)(ws + alloc((size_t)E_EDGES*4));
  int* pos_col      = (int*)(ws + alloc((size_t)E_EDGES*4));
  int* node_of_pos  = (int*)(ws + alloc((size_t)E_EDGES*4));
  unsigned short* Wp = (unsigned short*)(ws + alloc((size_t)2*OUT_DIM*KPH*2));
  float* out_acc    = (float*)(ws + alloc((size_t)N_NODES*OUT_DIM*4));
  uint2* cntb       = (uint2*)(ws + alloc((size_t)E_EDGES*8));
  unsigned short* msgN = (unsigned short*)(ws + alloc((size_t)NROWS_B*KPH*2));
  unsigned short* msg  = (unsigned short*)(ws + alloc((size_t)E_EDGES*KPH*2));
  (void)off; // ~192 MB total, fits the 256 MiB workspace

  unsigned short* Wp_in  = Wp;
  unsigned short* Wp_out = Wp + (size_t)OUT_DIM*KPH;

  // 1) sniff + all zero-fills
  k_init<<<2048, 256, 0, stream>>>(x, dflag, cnt, out_acc, msgN);
  // 2) edge vectors + degree hist + W pack
  k_prep<<<MT_A + 480, 256, 0, stream>>>(pos, W, row, col, vecn, cnt, Wp, dflag);
  // 3-5) scan (unchanged, proven)
  k_scan1<<<2*NSEG, SEG, 0, stream>>>(cnt, start2, segsum);
  k_scan2<<<1, 64, 0, stream>>>(segsum);
  k_scan3<<<2*NSEG, SEG, 0, stream>>>(start2, fill2, segsum);
  // 6) CSR scatter
  k_scatter<<<(E_EDGES+255)/256, 256, 0, stream>>>(row, col, fill2,
                                                   list_row, list_col, pos_col, node_of_pos);
  // 7) half-0 per-edge rows + cntb export (epilogue-only addition)
  k_msg_node<<<N_NODES, 256, 0, stream>>>(x, eattr, vecn, row, col, start2,
                                          list_row, list_col, pos_col, msg, cntb, dflag, 0);
  // 8) half-1 node rows from counts (no binning, no chist)
  k_msg1<<<(N_NODES+3)/4, 256, 0, stream>>>(x, eattr, col, start2,
                                            list_row, pos_col, cntb, msgN, dflag);
  // 9) GEMM-A: edge rows (bias added per edge row, segment-summed by dest node)
  k_gemm<<<dim3(2*MT_A), 256, 0, stream>>>(msg, Wp_in, bmsg, dflag,
                                           node_of_pos, out_acc, 1, 0, MT_A);
  // 10) GEMM-B: node rows (half-1 collapsed; no bias; row id == node id)
  k_gemm<<<dim3(2*MT_B), 256, 0, stream>>>(msgN, Wp_out, bmsg, dflag,
                                           node_of_pos, out_acc, 0, 1, MT_B);
  // 11) emit
  k_out<<<(N_NODES*OUT_DIM+255)/256, 256, 0, stream>>>(out_acc, d_out, dflag);
}

// Round 14
// 309.563 us; speedup vs baseline: 1.1123x; 1.0017x over previous
//
#include <hip/hip_runtime.h>
#include <stdint.h>

#define N_NODES 20000
#define E_EDGES 160000
#define C_DIM 32
#define OUT_DIM 128
#define K_REAL 910
#define KPH 480           // padded per-half K (448 feat + 7 e + cnt/pad 25), 15 x 32
#define DEG_CAP 64
#define SEG 1024
#define NSEG 20           // ceil(20000/1024)
#define MT_A (E_EDGES/256)    // 625 m-tiles, edge-row GEMM
#define NROWS_B 20224         // 79*256, node-row GEMM (rows 20000.. are zero pad)
#define MT_B (NROWS_B/256)    // 79
#define PADW ((NROWS_B - N_NODES)*KPH/2)   // msgN pad words (ints)

typedef __attribute__((ext_vector_type(4))) float f32x4;
typedef __attribute__((ext_vector_type(8))) short short8;

__device__ __forceinline__ float bf2f(unsigned short u){
  union { unsigned int i; float f; } v; v.i = ((unsigned int)u) << 16; return v.f;
}
__device__ __forceinline__ unsigned short f2bf(float f){
  union { float f; unsigned int i; } v; v.f = f;
  unsigned int i = v.i;
  unsigned int r = (i + 0x7FFFu + ((i >> 16) & 1u)) >> 16;
  return (unsigned short)r;
}
__device__ __forceinline__ float ldv(const void* p, size_t i, int isbf){
  return isbf ? bf2f(((const unsigned short*)p)[i]) : ((const float*)p)[i];
}
__device__ __forceinline__ int clampi(int v, int hi){  // [0, hi)
  return ((unsigned)v < (unsigned)hi) ? v : 0;
}

// ---------------- init: dtype sniff + ALL zero-fills (1 launch) ----------------
__global__ void k_init(const void* __restrict__ xraw, int* __restrict__ flag,
                       int* __restrict__ cnt, float* __restrict__ out_acc,
                       unsigned short* __restrict__ msgN)
{
  int tid = threadIdx.x;
  if (blockIdx.x == 0){
    __shared__ int s_bad;
    if (tid == 0) s_bad = 0;
    __syncthreads();
    float v = bf2f(((const unsigned short*)xraw)[tid * 2499]);
    if (!(fabsf(v) < 100.0f)) s_bad = 1;
    __syncthreads();
    if (tid == 0) flag[0] = s_bad ? 0 : 1; // 1 = bf16, 0 = fp32
  }
  const int Z1 = 2*N_NODES;                 // cnt ints
  const int Z2 = Z1 + N_NODES*OUT_DIM;      // + out_acc ints
  const int Z3 = Z2 + PADW;                 // + msgN pad ints
  int* padp = (int*)(msgN + (size_t)N_NODES*KPH);
  for (int i = blockIdx.x*blockDim.x + tid; i < Z3; i += gridDim.x*blockDim.x){
    if (i < Z1) cnt[i] = 0;
    else if (i < Z2) ((int*)out_acc)[i - Z1] = 0;
    else padp[i - Z2] = 0;
  }
}

// ---------------- prep: edge vectors + degree hist + W pack (block-split) ----------------
__global__ void k_prep(const void* __restrict__ pos, const void* __restrict__ W,
                       const int* __restrict__ row, const int* __restrict__ col,
                       float* __restrict__ vecn, int* __restrict__ cnt,
                       unsigned short* __restrict__ Wp,
                       const int* __restrict__ flg)
{
  int isbf = flg[0];
  if (blockIdx.x < MT_A){                      // build part
    int e = blockIdx.x*256 + threadIdx.x;
    if (e >= E_EDGES) return;
    int r = clampi(row[e], N_NODES), c = clampi(col[e], N_NODES);
    float vx = ldv(pos, (size_t)c*3+0, isbf) - ldv(pos, (size_t)r*3+0, isbf);
    float vy = ldv(pos, (size_t)c*3+1, isbf) - ldv(pos, (size_t)r*3+1, isbf);
    float vz = ldv(pos, (size_t)c*3+2, isbf) - ldv(pos, (size_t)r*3+2, isbf);
    float nn = sqrtf(vx*vx + vy*vy + vz*vz);
    f32x4 vv; vv[0]=vx; vv[1]=vy; vv[2]=vz; vv[3]=nn;
    *(f32x4*)(vecn + (size_t)e*4) = vv;
    atomicAdd(cnt + r, 1);
    atomicAdd(cnt + N_NODES + c, 1);
  } else {                                     // packw part (aligned layout)
    int i = (blockIdx.x - MT_A)*256 + threadIdx.x;
    if (i >= 2*OUT_DIM*KPH) return;
    int half = i / (OUT_DIM*KPH);
    int rem = i - half*OUT_DIM*KPH;
    int o = rem / KPH, kp = rem - o*KPH;
    float v = 0.f;
    if (kp < 448){
      int t = kp >> 6, f = kp & 63;
      v = ldv(W, (size_t)o*K_REAL + (2*t + half)*65 + f, isbf);
    } else if (kp < 455){
      int t = kp - 448;
      v = ldv(W, (size_t)o*K_REAL + (2*t + half)*65 + 64, isbf);
    }
    // kp in [455,480): Wp = 0 -> A-row pad bytes (455..479) multiply by zero,
    // so the count words stashed there by k_msg_node never affect the GEMM.
    Wp[i] = f2bf(v);
  }
}

// ---------------- 3-phase exclusive scan over cnt[2N] ----------------
__global__ void k_scan1(const int* __restrict__ cnt, int* __restrict__ start2,
                        int* __restrict__ segsum){
  __shared__ int buf[SEG];
  int b = blockIdx.x, arr = b / NSEG, seg = b - arr*NSEG;
  const int* cntp = cnt + (size_t)arr*N_NODES;
  int* startp = start2 + (size_t)arr*(N_NODES+1);
  int tid = threadIdx.x;
  int i = seg*SEG + tid;
  int v = (i < N_NODES) ? cntp[i] : 0;
  buf[tid] = v;
  __syncthreads();
  for (int off = 1; off < SEG; off <<= 1){
    int t = (tid >= off) ? buf[tid-off] : 0;
    __syncthreads();
    buf[tid] += t;
    __syncthreads();
  }
  if (i < N_NODES) startp[i] = buf[tid] - v;
  if (tid == SEG-1) segsum[b] = buf[tid];
}
__global__ void k_scan2(int* segsum){
  int tid = threadIdx.x;
  if (tid < 2){
    int run = 0;
    for (int s = 0; s < NSEG; ++s){
      int v = segsum[tid*NSEG+s]; segsum[tid*NSEG+s] = run; run += v;
    }
  }
}
__global__ void k_scan3(int* __restrict__ start2, int* __restrict__ fill2,
                        const int* __restrict__ segsum){
  int b = blockIdx.x, arr = b / NSEG, seg = b - arr*NSEG;
  int* startp = start2 + (size_t)arr*(N_NODES+1);
  int* fillp  = fill2  + (size_t)arr*N_NODES;
  int tid = threadIdx.x;
  int i = seg*SEG + tid;
  int add = segsum[b];
  if (i < N_NODES){ int s = startp[i] + add; startp[i] = s; fillp[i] = s; }
  if (b == 0 && tid == 0){
    start2[N_NODES] = E_EDGES;
    start2[(N_NODES+1) + N_NODES] = E_EDGES;
  }
}

// ---------------- scatter edge ids into CSR lists (+ inverse col perm + node of pos) ----------------
__global__ void k_scatter(const int* __restrict__ row, const int* __restrict__ col,
                          int* fill2, int* list_row, int* list_col,
                          int* pos_col, int* node_of_pos)
{
  int e = blockIdx.x*blockDim.x + threadIdx.x;
  if (e >= E_EDGES) return;
  int r = clampi(row[e], N_NODES), c = clampi(col[e], N_NODES);
  int p = atomicAdd(fill2 + r, 1);
  if ((unsigned)p < E_EDGES) list_row[p] = e;
  int q = atomicAdd(fill2 + N_NODES + c, 1);
  if ((unsigned)q < E_EDGES){ list_col[q] = e; node_of_pos[q] = c; }
  pos_col[e] = clampi(q, E_EDGES);
}

// ---------------- node-centric message build (R13 + counts stashed in the row PAD) ----------------
// Inner loop and all store addresses byte-identical to R13 EXCEPT: the 25-lane
// pad store now carries the 7 pair-bin counts at mrow[456..462] (u16). These
// multiply against zero Wp columns in the GEMM, so they are free to transport.
// No separate cntb buffer -> no scattered 8B stores, no write-allocate blowup.
__global__ __launch_bounds__(256)
void k_msg_node(const void* __restrict__ x, const void* __restrict__ eattr,
                const float* __restrict__ vecn,
                const int* __restrict__ row, const int* __restrict__ col,
                const int* __restrict__ start2,
                const int* __restrict__ list_row, const int* __restrict__ list_col,
                const int* __restrict__ pos_col,
                unsigned short* __restrict__ msg,
                const int* __restrict__ flg, int half)
{
  __shared__ int posT[DEG_CAP];
  __shared__ int othS[DEG_CAP];
  __shared__ float vS[DEG_CAP][4], vT[DEG_CAP][4];
  __shared__ float eS[DEG_CAP];
  __shared__ unsigned short fS[DEG_CAP][64];       // bf16: keeps LDS at 17.4 KB -> 8 blocks/CU
  __shared__ float e64[DEG_CAP][8];
  __shared__ unsigned char bins[DEG_CAP][DEG_CAP]; // [target][source], 0-padded

  const float cb1 = 0.9009688679f, cb2 = 0.6234898019f, cb3 = 0.2225209340f;
  const int* start_row = start2;
  const int* start_col = start2 + (N_NODES+1);
  int j = blockIdx.x;
  int tid = threadIdx.x, wv = tid >> 6, lane = tid & 63;
  int clo = start_col[j], chi = start_col[j+1];
  int rlo = start_row[j], rhi = start_row[j+1];
  if (clo < 0) clo = 0; if (chi > E_EDGES) chi = E_EDGES; if (chi < clo) chi = clo;
  if (rlo < 0) rlo = 0; if (rhi > E_EDGES) rhi = E_EDGES; if (rhi < rlo) rhi = rlo;
  int nI = chi - clo, nO = rhi - rlo;
  int nS = half ? nO : nI;
  int nT = half ? nI : nO;
  int slo = half ? rlo : clo;
  int tlo = half ? clo : rlo;
  const int* slist = half ? list_row : list_col;
  const int* tlist = half ? list_col : list_row;
  if (nT == 0) return;
  int isbf = flg[0];

  if (nS <= DEG_CAP && nT <= DEG_CAP){
    int nS4 = (nS + 3) & ~3;
    if (tid < nS){
      int s = clampi(slist[slo+tid], E_EDGES);
      othS[tid] = clampi(half ? col[s] : row[s], N_NODES);
      eS[tid] = ldv(eattr, s, isbf);
      vS[tid][0]=vecn[s*4+0]; vS[tid][1]=vecn[s*4+1];
      vS[tid][2]=vecn[s*4+2]; vS[tid][3]=vecn[s*4+3];
    }
    if (tid < nT){
      int t = clampi(tlist[tlo+tid], E_EDGES);
      posT[tid] = clampi(pos_col[t], E_EDGES);
      vT[tid][0]=vecn[t*4+0]; vT[tid][1]=vecn[t*4+1];
      vT[tid][2]=vecn[t*4+2]; vT[tid][3]=vecn[t*4+3];
    }
    for (int i = tid; i < DEG_CAP*8; i += 256) ((float*)e64)[i] = 0.f;
    { uint4 z = {0,0,0,0};                       // zero bins (pad cols read as t=0)
      ((uint4*)bins)[tid] = z; }
    __syncthreads();
    // stage source features: half=0 -> [x[other]|x[j]], half=1 -> [x[j]|x[other]]
    for (int cidx = tid; cidx < nS*64; cidx += 256){
      int si = cidx >> 6, f = cidx & 63;
      int lo_node = half ? j : othS[si];
      int hi_node = half ? othS[si] : j;
      int src = (f < 32) ? (lo_node*C_DIM + f) : (hi_node*C_DIM + f - 32);
      fS[si][f] = f2bf(ldv(x, (size_t)src, isbf));
    }
    // zero pad rows [nS, nS4) so pad (t=0) adds 0 to S0
    for (int i = tid; i < (nS4 - nS)*64; i += 256)
      fS[nS + (i >> 6)][i & 63] = 0;
    // pair bins (+ eattr accumulation per (target, bin))
    for (int p = tid; p < nS*64; p += 256){
      int si = p >> 6, ti = p & 63;
      if (ti < nT){
        float dot = -(vS[si][0]*vT[ti][0] + vS[si][1]*vT[ti][1] + vS[si][2]*vT[ti][2]);
        float cv = dot / (vS[si][3]*vT[ti][3] + 1e-8f);
        int t = (cv<=cb1)+(cv<=cb2)+(cv<=cb3)+(cv<=-cb3)+(cv<=-cb2)+(cv<=-cb1);
        bins[ti][si] = (unsigned char)t;
        atomicAdd(&e64[ti][t], eS[si]);
      }
    }
    __syncthreads();
    for (int ti = wv; ti < nT; ti += 4){
      float S0=0,S1=0,S2=0,S3=0,S4=0,S5=0,S6=0;
      const unsigned* brow = (const unsigned*)bins[ti];
      for (int s4 = 0; s4 < nS4; s4 += 4){
        // bins row is wave-uniform -> scalarize the bin dispatch
        unsigned bb = (unsigned)__builtin_amdgcn_readfirstlane((int)brow[s4 >> 2]);
        #pragma unroll
        for (int u = 0; u < 4; ++u){
          int t = (bb >> (8*u)) & 7;
          float val = bf2f(fS[s4 + u][lane]);    // pad rows are 0
          switch(t){
            case 0: S0+=val; break; case 1: S1+=val; break; case 2: S2+=val; break;
            case 3: S3+=val; break; case 4: S4+=val; break; case 5: S5+=val; break;
            default: S6+=val; break;
          }
        }
      }
      // aligned layout: feature stores at t*64 -> 64B-aligned 128B segments
      unsigned short* mrow = msg + (size_t)posT[ti]*KPH;
      mrow[0*64+lane]=f2bf(S0); mrow[1*64+lane]=f2bf(S1); mrow[2*64+lane]=f2bf(S2);
      mrow[3*64+lane]=f2bf(S3); mrow[4*64+lane]=f2bf(S4); mrow[5*64+lane]=f2bf(S5);
      mrow[6*64+lane]=f2bf(S6);
      if (lane < 7)  mrow[448+lane] = f2bf(e64[ti][lane]);
      // pair-bin counts via ballot over the bins row (already in LDS), stored
      // into the SAME pad store that previously wrote zeros: counts at 456..462.
      int myb = (lane < nS) ? (int)bins[ti][lane] : 7;
      unsigned n0 = (unsigned)__popcll(__ballot(myb==0));
      unsigned n1 = (unsigned)__popcll(__ballot(myb==1));
      unsigned n2 = (unsigned)__popcll(__ballot(myb==2));
      unsigned n3 = (unsigned)__popcll(__ballot(myb==3));
      unsigned n4 = (unsigned)__popcll(__ballot(myb==4));
      unsigned n5 = (unsigned)__popcll(__ballot(myb==5));
      unsigned n6 = (unsigned)__popcll(__ballot(myb==6));
      if (lane < 25){
        unsigned short v = 0;
        if (lane >= 1 && lane <= 7){
          unsigned sel = (lane==1)?n0:(lane==2)?n1:(lane==3)?n2:(lane==4)?n3
                       : (lane==5)?n4:(lane==6)?n5:n6;
          v = (unsigned short)sel;
        }
        mrow[455+lane] = v;
      }
    }
  } else {
    // degree > cap fallback: all-global (correct, ~never taken)
    for (int ti = wv; ti < nT; ti += 4){
      int te = clampi(tlist[tlo+ti], E_EDGES);
      float tx=vecn[te*4+0], ty=vecn[te*4+1], tz=vecn[te*4+2], tn=vecn[te*4+3];
      float S0=0,S1=0,S2=0,S3=0,S4=0,S5=0,S6=0,S64v=0;
      int n0=0,n1=0,n2=0,n3=0,n4=0,n5=0,n6=0;
      for (int si = 0; si < nS; ++si){
        int se = clampi(slist[slo+si], E_EDGES);
        float dot = -(vecn[se*4+0]*tx + vecn[se*4+1]*ty + vecn[se*4+2]*tz);
        float cv = dot / (vecn[se*4+3]*tn + 1e-8f);
        int tv = (cv<=cb1)+(cv<=cb2)+(cv<=cb3)+(cv<=-cb3)+(cv<=-cb2)+(cv<=-cb1);
        int t = __builtin_amdgcn_readfirstlane(tv);
        int oth = clampi(half ? col[se] : row[se], N_NODES);
        int lo_node = half ? j : oth;
        int hi_node = half ? oth : j;
        float val = (lane < 32) ? ldv(x, (size_t)lo_node*C_DIM+lane, isbf)
                                : ldv(x, (size_t)hi_node*C_DIM+lane-32, isbf);
        switch(t){
          case 0: S0+=val; n0++; break; case 1: S1+=val; n1++; break;
          case 2: S2+=val; n2++; break; case 3: S3+=val; n3++; break;
          case 4: S4+=val; n4++; break; case 5: S5+=val; n5++; break;
          default: S6+=val; n6++; break;
        }
        S64v += (lane == t) ? ldv(eattr, se, isbf) : 0.f;
      }
      unsigned short* mrow = msg + (size_t)clampi(pos_col[te], E_EDGES)*KPH;
      mrow[0*64+lane]=f2bf(S0); mrow[1*64+lane]=f2bf(S1); mrow[2*64+lane]=f2bf(S2);
      mrow[3*64+lane]=f2bf(S3); mrow[4*64+lane]=f2bf(S4); mrow[5*64+lane]=f2bf(S5);
      mrow[6*64+lane]=f2bf(S6);
      if (lane < 7)  mrow[448+lane] = f2bf(S64v);
      if (lane < 25){
        unsigned short v = 0;
        if (lane >= 1 && lane <= 7){
          int sel = (lane==1)?n0:(lane==2)?n1:(lane==3)?n2:(lane==4)?n3
                  : (lane==5)?n4:(lane==6)?n5:n6;
          v = (unsigned short)((sel > 65535) ? 65535 : sel);
        }
        mrow[455+lane] = v;
      }
    }
  }
}

// ---------------- half-1 node rows: counts read from the msg-row pad ----------------
// MSG1[j,t,:] = sum_{out-edges b of j} cnt_t(b) * [x_j | x_col[b] | e_b].
// Counts live at msg[pos][456..462] (u16, 16B-aligned load) -> no binning, no
// chist, no separate cntb gather. Wave-per-node, lane-parallel metadata +
// 8-deep shfl-broadcast gather window.
__global__ __launch_bounds__(256)
void k_msg1(const void* __restrict__ x, const void* __restrict__ eattr,
            const int* __restrict__ col,
            const int* __restrict__ start2,
            const int* __restrict__ list_row, const int* __restrict__ pos_col,
            const unsigned short* __restrict__ msg,
            unsigned short* __restrict__ msgN,
            const int* __restrict__ flg)
{
  int wv = threadIdx.x >> 6, lane = threadIdx.x & 63;
  int j = blockIdx.x*4 + wv;
  if (j >= N_NODES) return;
  int isbf = flg[0];
  unsigned short* mrow = msgN + (size_t)j*KPH;
  int rlo = start2[j], rhi = start2[j+1];
  if (rlo < 0) rlo = 0; if (rhi > E_EDGES) rhi = E_EDGES; if (rhi < rlo) rhi = rlo;
  int nT = rhi - rlo;
  if (nT == 0){
    for (int i = lane; i < KPH; i += 64) mrow[i] = 0;
    return;
  }
  float xj = ldv(x, (size_t)j*C_DIM + (lane & 31), isbf);
  float m0=0,m1=0,m2=0,m3=0,m4=0,m5=0,m6=0;
  float me0=0,me1=0,me2=0,me3=0,me4=0,me5=0,me6=0;

  for (int tb = 0; tb < nT; tb += 64){
    int nn = nT - tb; if (nn > 64) nn = 64;
    // lane-parallel metadata for this chunk of targets
    int ok = lane < nn;
    int te = ok ? clampi(list_row[rlo + tb + lane], E_EDGES) : 0;
    int pp = clampi(pos_col[te], E_EDGES);
    // counts: ushort8 at row offset 456 (912B from 960B-aligned base -> 16B-aligned)
    short8 cc = *(const short8*)(msg + (size_t)pp*KPH + 456);
    unsigned c01L = ok ? (((unsigned)(unsigned short)cc[0]) | (((unsigned)(unsigned short)cc[1]) << 16)) : 0u;
    unsigned c23L = ok ? (((unsigned)(unsigned short)cc[2]) | (((unsigned)(unsigned short)cc[3]) << 16)) : 0u;
    unsigned c45L = ok ? (((unsigned)(unsigned short)cc[4]) | (((unsigned)(unsigned short)cc[5]) << 16)) : 0u;
    unsigned c6L  = ok ? ((unsigned)(unsigned short)cc[6]) : 0u;
    int oL = clampi(col[te], N_NODES);
    float eL = ok ? ldv(eattr, te, isbf) : 0.f;

    for (int u = 0; u < nn; u += 8){
      float v[8], ea[8];
      unsigned ca[8], cb[8], cd[8], ce[8];
      #pragma unroll
      for (int q = 0; q < 8; ++q){
        int ti = u + q;
        int o = __shfl(oL, ti);
        unsigned c01 = (unsigned)__shfl((int)c01L, ti);
        unsigned c23 = (unsigned)__shfl((int)c23L, ti);
        unsigned c45 = (unsigned)__shfl((int)c45L, ti);
        unsigned c6  = (unsigned)__shfl((int)c6L, ti);
        float eb = __shfl(eL, ti);
        if (ti < nn){
          v[q] = (lane < 32) ? xj : ldv(x, (size_t)o*C_DIM + lane - 32, isbf);
          ca[q] = c01; cb[q] = c23; cd[q] = c45; ce[q] = c6; ea[q] = eb;
        } else {
          v[q] = 0.f; ca[q] = 0u; cb[q] = 0u; cd[q] = 0u; ce[q] = 0u; ea[q] = 0.f;
        }
      }
      #pragma unroll
      for (int q = 0; q < 8; ++q){
        float n0=(float)(ca[q]&0xffffu), n1=(float)(ca[q]>>16),
              n2=(float)(cb[q]&0xffffu), n3=(float)(cb[q]>>16),
              n4=(float)(cd[q]&0xffffu), n5=(float)(cd[q]>>16),
              n6=(float)ce[q];
        m0+=n0*v[q]; m1+=n1*v[q]; m2+=n2*v[q]; m3+=n3*v[q];
        m4+=n4*v[q]; m5+=n5*v[q]; m6+=n6*v[q];
        me0+=n0*ea[q]; me1+=n1*ea[q]; me2+=n2*ea[q]; me3+=n3*ea[q];
        me4+=n4*ea[q]; me5+=n5*ea[q]; me6+=n6*ea[q];
      }
    }
  }

  mrow[0*64+lane]=f2bf(m0); mrow[1*64+lane]=f2bf(m1); mrow[2*64+lane]=f2bf(m2);
  mrow[3*64+lane]=f2bf(m3); mrow[4*64+lane]=f2bf(m4); mrow[5*64+lane]=f2bf(m5);
  mrow[6*64+lane]=f2bf(m6);
  if (lane < 7){
    float me = (lane==0)?me0:(lane==1)?me1:(lane==2)?me2:(lane==3)?me3
             : (lane==4)?me4:(lane==5)?me5:me6;
    mrow[448+lane] = f2bf(me);
  }
  if (lane < 25) mrow[455+lane] = 0;
}

// ---------------- merged GEMM: [0,2*MT_A) edge rows + bias; rest node rows ident ----------------
// Proven body; XCD pairing remap applied within each segment (pairs stay 8
// apart in blockIdx -> same XCD under round-robin).
__global__ __launch_bounds__(256)
void k_gemmN(const unsigned short* __restrict__ msg,
             const unsigned short* __restrict__ Wp_in,
             const unsigned short* __restrict__ msgN,
             const unsigned short* __restrict__ Wp_out,
             const void* __restrict__ bias,
             const int* __restrict__ flg,
             const int* __restrict__ node_of_pos,
             float* __restrict__ out_acc)
{
  __shared__ union {
    unsigned short Bs[64*512];     // 65536 B (60 of 64 chunk slots used per row)
    float seg[256][66];            // 67584 B, reused after K-loop
  } sh;
  __shared__ int nids[256];

  int tid = threadIdx.x;
  int w = tid >> 6, lane = tid & 63;
  int lrow = lane & 15, q = lane >> 4;

  int which = (blockIdx.x >= 2*MT_A) ? 1 : 0;
  int lin = blockIdx.x - which*2*MT_A;
  const unsigned short* A  = which ? msgN  : msg;
  const unsigned short* Wp = which ? Wp_out : Wp_in;
  int mtiles  = which ? MT_B : MT_A;
  int addbias = !which;
  int ident   = which;

  const int FULLG = (mtiles & ~7) * 2;
  int mt, ch;
  if (lin < FULLG){
    mt = (lin >> 4)*8 + (lin & 7);       // ids L and L+8 share mt's A-tile
    ch = (lin >> 3) & 1;
  } else {
    int r2 = lin - FULLG;
    mt = (mtiles & ~7) + (r2 >> 1);
    ch = r2 & 1;
  }
  int m0 = mt * 256;

  nids[tid] = ident ? ((m0 + tid < N_NODES) ? m0 + tid : N_NODES-1)
                    : clampi(node_of_pos[m0 + tid], N_NODES);

  // A prologue: issue 3 k-steps of loads early (overlaps with B staging)
  const unsigned short* abase = A + (size_t)(m0 + w*64 + lrow)*KPH + q*8;
  short8 apf[3][4];
  #pragma unroll
  for (int d = 0; d < 3; ++d)
    #pragma unroll
    for (int rf = 0; rf < 4; ++rf)
      apf[d][rf] = *(const short8*)(abase + (size_t)rf*16*KPH + d*32);

  // stage B once: 64 rows x 60 chunks of 16B
  #pragma unroll
  for (int i = 0; i < 15; ++i){
    int idx = tid + i*256;
    int rr = idx / 60, cc = idx - rr*60;
    const uint4* gq = (const uint4*)(Wp + (size_t)(ch*64 + rr)*KPH + cc*8);
    *(uint4*)(sh.Bs + rr*512 + ((cc ^ (rr & 7))*8)) = *gq;
  }
  __syncthreads();

  f32x4 acc[4][4];
  #pragma unroll
  for (int rf = 0; rf < 4; ++rf)
    #pragma unroll
    for (int nf = 0; nf < 4; ++nf) acc[rf][nf] = (f32x4)0.f;

  #pragma unroll
  for (int k0i = 0; k0i < 15; ++k0i){
    int cur = k0i % 3;
    int c = k0i*4 + q;               // B chunk index 0..59
    #pragma unroll
    for (int nf = 0; nf < 4; ++nf){
      int rb = nf*16 + lrow;
      short8 bfr = *(const short8*)(sh.Bs + rb*512 + ((c ^ (rb & 7))*8));
      #pragma unroll
      for (int rf = 0; rf < 4; ++rf)
        acc[rf][nf] = __builtin_amdgcn_mfma_f32_16x16x32_bf16(apf[cur][rf], bfr, acc[rf][nf], 0, 0, 0);
    }
    if (k0i + 3 < 15){               // refill just-consumed buffer (3-step window)
      #pragma unroll
      for (int rf = 0; rf < 4; ++rf)
        apf[cur][rf] = *(const short8*)(abase + (size_t)rf*16*KPH + (k0i+3)*32);
    }
  }

  int isbf = flg[0];
  float bvs[4];
  #pragma unroll
  for (int nf = 0; nf < 4; ++nf)
    bvs[nf] = addbias ? ldv(bias, ch*64 + nf*16 + lrow, isbf) : 0.f;

  // single-phase epilogue: all waves dump fragments, then 4 groups reduce concurrently
  __syncthreads();                   // Bs dead from here
  #pragma unroll
  for (int rf = 0; rf < 4; ++rf)
    #pragma unroll
    for (int r = 0; r < 4; ++r){
      int m = w*64 + rf*16 + q*4 + r;
      #pragma unroll
      for (int nf = 0; nf < 4; ++nf)
        sh.seg[m][nf*16 + lrow] = acc[rf][nf][r] + bvs[nf];
    }
  __syncthreads();
  {
    int o = tid & 63, g = tid >> 6;  // 4 groups x 64 rows
    int base = g*64;
    float s = 0.f;
    int curn = nids[base];
    for (int r = 0; r < 64; ++r){
      int m = base + r;
      int nid = nids[m];
      if (nid != curn){
        atomicAdd(out_acc + (size_t)curn*OUT_DIM + ch*64 + o, s);
        s = 0.f; curn = nid;
      }
      s += sh.seg[m][o];
    }
    atomicAdd(out_acc + (size_t)curn*OUT_DIM + ch*64 + o, s);
  }
}

// ---------------- convert out_acc -> d_out per flag ----------------
__global__ void k_out(const float* __restrict__ acc, void* __restrict__ outp,
                      const int* __restrict__ flg){
  int i = blockIdx.x*blockDim.x + threadIdx.x;
  if (i >= N_NODES*OUT_DIM) return;
  if (flg[0]) ((unsigned short*)outp)[i] = f2bf(acc[i]);
  else        ((float*)outp)[i] = acc[i];
}

extern "C" void kernel_launch(void* const* d_in, const int* in_sizes, int n_in,
                              void* d_out, int out_size, void* d_ws, size_t ws_size,
                              hipStream_t stream)
{
  const void* x     = d_in[0];
  const void* eattr = d_in[1];
  const void* pos   = d_in[2];
  const void* W     = d_in[3];
  const void* bmsg  = d_in[4];
  const int* eidx = (const int*)d_in[5];
  const int* row = eidx;
  const int* col = eidx + E_EDGES;

  char* ws = (char*)d_ws;
  size_t off = 0;
  auto alloc = [&](size_t b){ size_t o = off; off += (b + 255) & ~(size_t)255; return o; };

  int* dflag        = (int*)(ws + alloc(256));
  float* vecn       = (float*)(ws + alloc((size_t)E_EDGES*16));
  int* cnt          = (int*)(ws + alloc((size_t)2*N_NODES*4));
  int* start2       = (int*)(ws + alloc((size_t)2*(N_NODES+1)*4));
  int* fill2        = (int*)(ws + alloc((size_t)2*N_NODES*4));
  int* segsum       = (int*)(ws + alloc((size_t)2*NSEG*4));
  int* list_row     = (int*)(ws + alloc((size_t)E_EDGES*4));
  int* list_col     = (int*)(ws + alloc((size_t)E_EDGES*4));
  int* pos_col      = (int*)(ws + alloc((size_t)E_EDGES*4));
  int* node_of_pos  = (int*)(ws + alloc((size_t)E_EDGES*4));
  unsigned short* Wp = (unsigned short*)(ws + alloc((size_t)2*OUT_DIM*KPH*2));
  float* out_acc    = (float*)(ws + alloc((size_t)N_NODES*OUT_DIM*4));
  unsigned short* msgN = (unsigned short*)(ws + alloc((size_t)NROWS_B*KPH*2));
  unsigned short* msg  = (unsigned short*)(ws + alloc((size_t)E_EDGES*KPH*2));
  (void)off; // ~190 MB total, fits the 256 MiB workspace

  unsigned short* Wp_in  = Wp;
  unsigned short* Wp_out = Wp + (size_t)OUT_DIM*KPH;

  // 1) sniff + all zero-fills
  k_init<<<2048, 256, 0, stream>>>(x, dflag, cnt, out_acc, msgN);
  // 2) edge vectors + degree hist + W pack
  k_prep<<<MT_A + 480, 256, 0, stream>>>(pos, W, row, col, vecn, cnt, Wp, dflag);
  // 3-5) scan (unchanged, proven)
  k_scan1<<<2*NSEG, SEG, 0, stream>>>(cnt, start2, segsum);
  k_scan2<<<1, 64, 0, stream>>>(segsum);
  k_scan3<<<2*NSEG, SEG, 0, stream>>>(start2, fill2, segsum);
  // 6) CSR scatter
  k_scatter<<<(E_EDGES+255)/256, 256, 0, stream>>>(row, col, fill2,
                                                   list_row, list_col, pos_col, node_of_pos);
  // 7) half-0 per-edge rows; counts ride in the row pad (zero extra stores)
  k_msg_node<<<N_NODES, 256, 0, stream>>>(x, eattr, vecn, row, col, start2,
                                          list_row, list_col, pos_col, msg, dflag, 0);
  // 8) half-1 node rows from pad counts (no binning, no chist)
  k_msg1<<<(N_NODES+3)/4, 256, 0, stream>>>(x, eattr, col, start2,
                                            list_row, pos_col, msg, msgN, dflag);
  // 9) merged GEMM: edge rows (+bias) and node rows in one launch
  k_gemmN<<<dim3(2*MT_A + 2*MT_B), 256, 0, stream>>>(msg, Wp_in, msgN, Wp_out,
                                                     bmsg, dflag, node_of_pos, out_acc);
  // 10) emit
  k_out<<<(N_NODES*OUT_DIM+255)/256, 256, 0, stream>>>(out_acc, d_out, dflag);
}